// Round 9
// baseline (397.592 us; speedup 1.0000x reference)
//
#include <hip/hip_runtime.h>

#define K_TOP  300
#define NCLS   80
#define NB     256
#define NF4    20000     // float4 per batch (80000 floats)
#define GTHR   2.2f      // static collect threshold; rank-300 sits at z~2.67
#define BPB    10        // collect blocks (chunks) per batch
#define CHUNK  2048      // float4 per chunk (last chunk ragged: 1568)
#define CAPC   256       // per-chunk candidate capacity (expect ~114 +/- 11)
#define NCAND  (BPB*CAPC)// 2560 per batch
#define NBK    1024      // bucket count (fast: o>>20 - 3072; fallback: o>>22)

typedef unsigned int       u32;
typedef unsigned long long u64;

__device__ __forceinline__ u32 order_f32(float f) {
    u32 u = __float_as_uint(f);
    return u ^ ((u >> 31) ? 0xFFFFFFFFu : 0x80000000u);
}
__device__ __forceinline__ float unorder_f32(u32 u) {
    u32 v = (u & 0x80000000u) ? (u ^ 0x80000000u) : ~u;
    return __uint_as_float(v);
}

// wave-aggregated LDS push: one atomic per wave per slot
__device__ __forceinline__ void wpush(float v, int idx, u64* sbuf, u32* scnt) {
    const bool win = (v >= GTHR);
    const u64 mask = __ballot(win);
    if (mask == 0ull) return;
    const int lane = threadIdx.x & 63;
    const int lead = __ffsll((unsigned long long)mask) - 1;
    u32 base = 0;
    if (lane == lead) base = atomicAdd(scnt, (u32)__popcll(mask));
    base = (u32)__shfl((int)base, lead);
    if (win) {
        u32 pos = base + (u32)__popcll(mask & ((1ull << lane) - 1ull));
        if (pos < CAPC) {
            u32 o = order_f32(v);
            sbuf[pos] = ((u64)o << 32) | (u64)(0xFFFFFFFFu - (u32)idx);
        }
    }
}

// exclusive-suffix scan over NBK=1024 buckets, 256 threads (4 buckets/thread,
// 16-bucket groups). On return hist[bk]=cur[bk]=start, *s_B = max bk with
// suffix(>=bk) >= K_TOP. Cross-lane hist reads stay within a 4-thread cluster
// (same wave -> lockstep-safe). Caller barriers before/after.
__device__ __forceinline__ void scan_buckets(u32* hist, u32* cur, u32* csum,
                                             int* s_B, int t) {
    if (t < 64) {
        u32 s = 0;
        for (int u = 0; u < 16; ++u) s += hist[16*t + u];
        csum[t] = s;
    }
    __syncthreads();
    if (t == 0) {   // exclusive suffix over 64 group sums
        u32 run = 0;
        for (int s = 63; s >= 0; --s) { u32 v = csum[s]; csum[s] = run; run += v; }
    }
    __syncthreads();
    const int g = t >> 2;
    u32 ex = csum[g];
    for (int j = 16*g + 15; j >= 4*t + 4; --j) ex += hist[j];
    u32 h0 = hist[4*t], h1 = hist[4*t+1], h2 = hist[4*t+2], h3 = hist[4*t+3];
    u32 st3 = ex, st2 = st3 + h3, st1 = st2 + h2, st0 = st1 + h1;
    int bl = -1;   // suffix(>=bk) non-increasing: first hit from top is max
    if      (st3 + h3 >= K_TOP) bl = 4*t + 3;
    else if (st2 + h2 >= K_TOP) bl = 4*t + 2;
    else if (st1 + h1 >= K_TOP) bl = 4*t + 1;
    else if (st0 + h0 >= K_TOP) bl = 4*t;
    if (bl >= 0) atomicMax(s_B, bl);
    hist[4*t] = st0; hist[4*t+1] = st1; hist[4*t+2] = st2; hist[4*t+3] = st3;
    cur [4*t] = st0; cur [4*t+1] = st1; cur [4*t+2] = st2; cur [4*t+3] = st3;
}

__device__ __forceinline__ void write_row(float* __restrict__ out, int b, int rank,
                                          u64 key, const float4* __restrict__ BX,
                                          float sx, float sy) {
    u32 o   = (u32)(key >> 32);
    u32 idx = ~((u32)key);
    float logit = unorder_f32(o);
    float score = 1.0f / (1.0f + expf(-logit));
    int label = (int)(idx % NCLS);
    int q     = (int)(idx / NCLS);
    float4 bx = BX[q];
    float* po = out + ((size_t)b * K_TOP + rank) * 6;
    po[0] = (float)label;
    po[1] = score;
    po[2] = (bx.x - 0.5f * bx.z) * sx;
    po[3] = (bx.y - 0.5f * bx.w) * sy;
    po[4] = bx.z * sx;
    po[5] = bx.w * sy;
}

// rank within own bucket segment (cand bucket-grouped); write top-300.
// bucket(key) = (key >> (32+shift)) - bias. 256-thread strides.
__device__ __forceinline__ void rank_and_write(const u64* cand, const u32* hist,
                                               const u32* cur, u32 B, int shift,
                                               u32 bias, int t, int b,
                                               const float4* BX, float sx, float sy,
                                               float* out) {
    int total = (int)cur[B]; if (total > NCAND) total = NCAND;
    for (int i = t; i < total; i += 256) {
        u64 key = cand[i];
        u32 bk   = (u32)(key >> (32 + shift)) - bias;
        int segS = (int)hist[bk];
        int segE = (int)cur[bk]; if (segE > NCAND) segE = NCAND;
        int r = segS;
        for (int j = segS; j < segE; ++j)
            r += (cand[j] > key) ? 1 : 0;
        if (r < K_TOP)
            write_row(out, b, r, key, BX, sx, sy);
    }
}

// full two-pass fallback for batch b (degenerate data / no workspace)
__device__ void full_fallback(const float* __restrict__ logits, int b, int t,
                              u64* cand, u32* hist, u32* cur, u32* csum, int* s_B,
                              const float4* BX, float sx, float sy,
                              float* __restrict__ out) {
    __syncthreads();
    for (int i = t; i < NBK; i += 256) { hist[i] = 0; cur[i] = 0; }
    if (t == 0) *s_B = -1;
    __syncthreads();
    const float4* L4 = (const float4*)(logits + (size_t)b * (NF4 * 4));
    for (int i = t; i < NF4; i += 256) {
        float4 v = L4[i];
        atomicAdd(&hist[order_f32(v.x) >> 22], 1u);
        atomicAdd(&hist[order_f32(v.y) >> 22], 1u);
        atomicAdd(&hist[order_f32(v.z) >> 22], 1u);
        atomicAdd(&hist[order_f32(v.w) >> 22], 1u);
    }
    __syncthreads();
    scan_buckets(hist, cur, csum, s_B, t);
    __syncthreads();
    const u32 B = (u32)*s_B;
    for (int i = t; i < NF4; i += 256) {
        float4 v = L4[i];
        float vv[4] = {v.x, v.y, v.z, v.w};
        #pragma unroll
        for (int u2 = 0; u2 < 4; ++u2) {
            u32 o = order_f32(vv[u2]);
            u32 bk = o >> 22;
            if (bk >= B) {
                u32 pos = atomicAdd(&cur[bk], 1u);
                if (pos < NCAND)
                    cand[pos] = ((u64)o << 32) |
                                (u64)(0xFFFFFFFFu - (u32)(4*i + u2));
            }
        }
    }
    __syncthreads();
    rank_and_write(cand, hist, cur, B, 22, 0u, t, b, BX, sx, sy, out);
}

// ---------------- fused: collect; last block of each batch selects ----------------
__global__ __launch_bounds__(256) void fused_kernel(
    const float* __restrict__ logits,
    const float* __restrict__ boxes,
    const int*   __restrict__ osz,
    u32* __restrict__ gcnt,
    u64* __restrict__ gbuf,
    u32* __restrict__ done,
    float* __restrict__ out)
{
    __shared__ u64 cand[NCAND];   // 20 KB; collect aliases first CAPC as sbuf
    __shared__ u32 hist[NBK];     // 4 KB
    __shared__ u32 cur[NBK];      // 4 KB
    __shared__ u32 csum[64];
    __shared__ u32 scc[BPB];
    __shared__ u32 scnt;
    __shared__ int s_B;
    __shared__ int s_sel;

    const int blk = blockIdx.x;
    const int b   = blk / BPB;          // const div -> magic mul
    const int c   = blk - b * BPB;
    const int t   = threadIdx.x;

    if (t == 0) scnt = 0;
    __syncthreads();

    // ---- collect phase: 8 loads in flight, ballot-aggregated pushes ----
    const float4* __restrict__ L4 = (const float4*)(logits + (size_t)b * (NF4 * 4));
    const int base4 = c * CHUNK;
    float4 v[8];
    #pragma unroll
    for (int j = 0; j < 8; ++j) {
        const int idx = base4 + j * 256 + t;
        v[j] = (idx < NF4) ? L4[idx]
                           : make_float4(-1e30f, -1e30f, -1e30f, -1e30f);
    }
    #pragma unroll
    for (int j = 0; j < 8; ++j) {
        const int i4 = (base4 + j * 256 + t) * 4;
        wpush(v[j].x, i4 + 0, cand, &scnt);
        wpush(v[j].y, i4 + 1, cand, &scnt);
        wpush(v[j].z, i4 + 2, cand, &scnt);
        wpush(v[j].w, i4 + 3, cand, &scnt);
    }
    __syncthreads();

    const u32 cnt = scnt;
    {
        u64* __restrict__ gb = gbuf + (size_t)blk * CAPC;   // private segment
        if (cnt <= CAPC) {
            if (t < (int)cnt) gb[t] = cand[t];
            if (t == 0) gcnt[blk] = cnt;
        } else {
            if (t == 0) gcnt[blk] = 0xFFFFFFFFu;            // overflow sentinel
        }
    }
    __threadfence();                 // release this thread's stores
    __syncthreads();
    if (t == 0) {
        u32 old = atomicAdd(&done[b], 1u);
        s_sel = (old == BPB - 1) ? 1 : 0;
    }
    __syncthreads();
    if (!s_sel) return;

    // ---- selector: last-finishing block performs batch b's select ----
    __threadfence();                 // acquire: see other blocks' stores

    if (t < BPB) scc[t] = gcnt[b * BPB + t];
    if (t == 0) s_B = -1;
    for (int i = t; i < NBK; i += 256) { hist[i] = 0; cur[i] = 0; }
    __syncthreads();

    bool fast = true;
    int total = 0;
    #pragma unroll
    for (int k = 0; k < BPB; ++k) {
        u32 x = scc[k];
        if (x > CAPC) fast = false; else total += (int)x;
    }
    fast = fast && (total >= K_TOP);

    const float sx = (float)osz[1];   // scale = [W, H, W, H]
    const float sy = (float)osz[0];
    const float4* BX = (const float4*)(boxes + (size_t)b * 4000);
    const u64* __restrict__ gb = gbuf + (size_t)b * NCAND;

    if (fast) {
        // histogram candidates into 1024 biased buckets (o>>20 in [3072,4095])
        for (int i = t; i < NCAND; i += 256) {
            int k = i >> 8, j = i & (CAPC - 1);
            if (j < (int)scc[k])
                atomicAdd(&hist[(u32)(gb[i] >> 52) - 3072u], 1u);
        }
        __syncthreads();
        scan_buckets(hist, cur, csum, &s_B, t);
        __syncthreads();
        fast = (s_B >= 1);   // B must be above GTHR's partial bucket
    }

    if (fast) {
        const u32 B = (u32)s_B;
        for (int i = t; i < NCAND; i += 256) {   // scatter bucket-grouped
            int k = i >> 8, j = i & (CAPC - 1);
            if (j < (int)scc[k]) {
                u64 key = gb[i];
                u32 pos = atomicAdd(&cur[(u32)(key >> 52) - 3072u], 1u);
                cand[pos] = key;   // pos < total <= NCAND guaranteed
            }
        }
        __syncthreads();
        rank_and_write(cand, hist, cur, B, 20, 3072u, t, b, BX, sx, sy, out);
    } else {
        full_fallback(logits, b, t, cand, hist, cur, csum, &s_B, BX, sx, sy, out);
    }
}

// no-workspace path: pure per-batch two-pass select
__global__ __launch_bounds__(256) void select_nows_kernel(
    const float* __restrict__ logits,
    const float* __restrict__ boxes,
    const int*   __restrict__ osz,
    float*       __restrict__ out)
{
    __shared__ u64 cand[NCAND];
    __shared__ u32 hist[NBK];
    __shared__ u32 cur[NBK];
    __shared__ u32 csum[64];
    __shared__ int s_B;
    const int b = blockIdx.x;
    const int t = threadIdx.x;
    const float sx = (float)osz[1];
    const float sy = (float)osz[0];
    const float4* BX = (const float4*)(boxes + (size_t)b * 4000);
    full_fallback(logits, b, t, cand, hist, cur, csum, &s_B, BX, sx, sy, out);
}

extern "C" void kernel_launch(void* const* d_in, const int* in_sizes, int n_in,
                              void* d_out, int out_size, void* d_ws, size_t ws_size,
                              hipStream_t stream) {
    const float* logits = (const float*)d_in[0];
    const float* boxes  = (const float*)d_in[1];
    const int*   osz    = (const int*)d_in[2];
    float* out = (float*)d_out;

    const size_t need = 16384 + (size_t)NB * NCAND * sizeof(u64);
    if (ws_size >= need) {
        u32* gcnt = (u32*)d_ws;                          // 2560 u32
        u32* done = (u32*)((char*)d_ws + 12288);         // 256 u32
        u64* gbuf = (u64*)((char*)d_ws + 16384);         // 2560*256 u64
        hipMemsetAsync(done, 0, NB * sizeof(u32), stream);
        fused_kernel<<<dim3(NB * BPB), dim3(256), 0, stream>>>(
            logits, boxes, osz, gcnt, gbuf, done, out);
    } else {
        select_nows_kernel<<<dim3(NB), dim3(256), 0, stream>>>(logits, boxes, osz, out);
    }
}

// Round 10
// 62.844 us; speedup vs baseline: 6.3267x; 6.3267x over previous
//
#include <hip/hip_runtime.h>

#define K_TOP  300
#define NCLS   80
#define NB     256
#define NF4    20000       // float4 per batch (80000 floats)
#define GTHR   2.2f        // static collect threshold; rank-300 sits at z~2.67
#define BPB    10          // collect blocks (chunks) per batch
#define CHUNK  2048        // float4 per chunk (last chunk ragged: 1568)
#define WPB    4           // waves per collect block
#define SEGC   96          // per-wave segment capacity (expect ~28.4 +/- 5.3)
#define NSEG   (BPB*WPB)   // 40 segments per batch
#define NCAND  (NSEG*SEGC) // 3840 per batch
#define NBK    1024        // bucket count (fast: o>>20 - 3072; fallback: o>>22)

typedef unsigned int       u32;
typedef unsigned long long u64;

__device__ __forceinline__ u32 order_f32(float f) {
    u32 u = __float_as_uint(f);
    return u ^ ((u >> 31) ? 0xFFFFFFFFu : 0x80000000u);
}
__device__ __forceinline__ float unorder_f32(u32 u) {
    u32 v = (u & 0x80000000u) ? (u ^ 0x80000000u) : ~u;
    return __uint_as_float(v);
}

// ---------------- kernel A: pure-stream collect, per-wave private segments ----
// ballot-aggregated: wave-uniform cursor (SGPR), no LDS, no barriers, no atomics
__device__ __forceinline__ u32 wstore(float v, int idx, u64* __restrict__ seg,
                                      u32 cursor, int lane) {
    const bool win = (v >= GTHR);
    const u64 mask = __ballot(win);
    if (mask) {
        if (win) {
            u32 pos = cursor + (u32)__popcll(mask & ((1ull << lane) - 1ull));
            if (pos < SEGC) {
                u32 o = order_f32(v);
                seg[pos] = ((u64)o << 32) | (u64)(0xFFFFFFFFu - (u32)idx);
            }
        }
        cursor += (u32)__popcll(mask);
    }
    return cursor;
}

__global__ __launch_bounds__(256) void collect_kernel(
    const float* __restrict__ logits,
    u32* __restrict__ gcnt,
    u64* __restrict__ gbuf)
{
    const int blk  = blockIdx.x;
    const int b    = blk / BPB;            // const div -> magic mul
    const int c    = blk - b * BPB;
    const int t    = threadIdx.x;
    const int lane = t & 63;
    const int wseg = blk * WPB + (t >> 6); // global wave-segment id

    const float4* __restrict__ L4 = (const float4*)(logits + (size_t)b * (NF4 * 4));
    const int base4 = c * CHUNK;

    // 8 independent loads in flight; only the last chunk is ragged
    float4 v[8];
    if (c < BPB - 1) {
        #pragma unroll
        for (int j = 0; j < 8; ++j) v[j] = L4[base4 + j * 256 + t];
    } else {
        #pragma unroll
        for (int j = 0; j < 8; ++j) {
            const int idx = base4 + j * 256 + t;
            v[j] = (idx < NF4) ? L4[idx]
                               : make_float4(-1e30f, -1e30f, -1e30f, -1e30f);
        }
    }

    u64* __restrict__ seg = gbuf + (size_t)wseg * SEGC;
    u32 cursor = 0;
    #pragma unroll
    for (int j = 0; j < 8; ++j) {
        const int i4 = (base4 + j * 256 + t) * 4;
        cursor = wstore(v[j].x, i4 + 0, seg, cursor, lane);
        cursor = wstore(v[j].y, i4 + 1, seg, cursor, lane);
        cursor = wstore(v[j].z, i4 + 2, seg, cursor, lane);
        cursor = wstore(v[j].w, i4 + 3, seg, cursor, lane);
    }
    if (lane == 0) gcnt[wseg] = cursor;    // > SEGC signals overflow -> fallback
}

// ---------------- kernel B: per-batch select / rank / write ----------------

// exclusive-suffix scan over NBK=1024 buckets, 256 threads (4 buckets/thread,
// 16-bucket groups). On return hist[bk]=cur[bk]=start, *s_B = max bk with
// suffix(>=bk) >= K_TOP. Caller barriers before/after. (proven in R9)
__device__ __forceinline__ void scan_buckets(u32* hist, u32* cur, u32* csum,
                                             int* s_B, int t) {
    if (t < 64) {
        u32 s = 0;
        for (int u = 0; u < 16; ++u) s += hist[16*t + u];
        csum[t] = s;
    }
    __syncthreads();
    if (t == 0) {   // exclusive suffix over 64 group sums
        u32 run = 0;
        for (int s = 63; s >= 0; --s) { u32 v = csum[s]; csum[s] = run; run += v; }
    }
    __syncthreads();
    const int g = t >> 2;
    u32 ex = csum[g];
    for (int j = 16*g + 15; j >= 4*t + 4; --j) ex += hist[j];
    u32 h0 = hist[4*t], h1 = hist[4*t+1], h2 = hist[4*t+2], h3 = hist[4*t+3];
    u32 st3 = ex, st2 = st3 + h3, st1 = st2 + h2, st0 = st1 + h1;
    int bl = -1;   // suffix(>=bk) non-increasing: first hit from top is max
    if      (st3 + h3 >= K_TOP) bl = 4*t + 3;
    else if (st2 + h2 >= K_TOP) bl = 4*t + 2;
    else if (st1 + h1 >= K_TOP) bl = 4*t + 1;
    else if (st0 + h0 >= K_TOP) bl = 4*t;
    if (bl >= 0) atomicMax(s_B, bl);
    hist[4*t] = st0; hist[4*t+1] = st1; hist[4*t+2] = st2; hist[4*t+3] = st3;
    cur [4*t] = st0; cur [4*t+1] = st1; cur [4*t+2] = st2; cur [4*t+3] = st3;
}

__device__ __forceinline__ void write_row(float* __restrict__ out, int b, int rank,
                                          u64 key, const float4* __restrict__ BX,
                                          float sx, float sy) {
    u32 o   = (u32)(key >> 32);
    u32 idx = ~((u32)key);
    float logit = unorder_f32(o);
    float score = 1.0f / (1.0f + expf(-logit));
    int label = (int)(idx % NCLS);
    int q     = (int)(idx / NCLS);
    float4 bx = BX[q];
    float* po = out + ((size_t)b * K_TOP + rank) * 6;
    po[0] = (float)label;
    po[1] = score;
    po[2] = (bx.x - 0.5f * bx.z) * sx;
    po[3] = (bx.y - 0.5f * bx.w) * sy;
    po[4] = bx.z * sx;
    po[5] = bx.w * sy;
}

// rank within own bucket segment (cand bucket-grouped); write top-300.
// bucket(key) = (key >> (32+shift)) - bias. 256-thread strides.
__device__ __forceinline__ void rank_and_write(const u64* cand, const u32* hist,
                                               const u32* cur, u32 B, int shift,
                                               u32 bias, int t, int b,
                                               const float4* BX, float sx, float sy,
                                               float* out) {
    int total = (int)cur[B]; if (total > NCAND) total = NCAND;
    for (int i = t; i < total; i += 256) {
        u64 key = cand[i];
        u32 bk   = (u32)(key >> (32 + shift)) - bias;
        int segS = (int)hist[bk];
        int segE = (int)cur[bk]; if (segE > NCAND) segE = NCAND;
        int r = segS;
        for (int j = segS; j < segE; ++j)
            r += (cand[j] > key) ? 1 : 0;
        if (r < K_TOP)
            write_row(out, b, r, key, BX, sx, sy);
    }
}

// full two-pass fallback for batch b (degenerate data / no workspace)
__device__ void full_fallback(const float* __restrict__ logits, int b, int t,
                              u64* cand, u32* hist, u32* cur, u32* csum, int* s_B,
                              const float4* BX, float sx, float sy,
                              float* __restrict__ out) {
    __syncthreads();
    for (int i = t; i < NBK; i += 256) { hist[i] = 0; cur[i] = 0; }
    if (t == 0) *s_B = -1;
    __syncthreads();
    const float4* L4 = (const float4*)(logits + (size_t)b * (NF4 * 4));
    for (int i = t; i < NF4; i += 256) {
        float4 v = L4[i];
        atomicAdd(&hist[order_f32(v.x) >> 22], 1u);
        atomicAdd(&hist[order_f32(v.y) >> 22], 1u);
        atomicAdd(&hist[order_f32(v.z) >> 22], 1u);
        atomicAdd(&hist[order_f32(v.w) >> 22], 1u);
    }
    __syncthreads();
    scan_buckets(hist, cur, csum, s_B, t);
    __syncthreads();
    const u32 B = (u32)*s_B;
    for (int i = t; i < NF4; i += 256) {
        float4 v = L4[i];
        float vv[4] = {v.x, v.y, v.z, v.w};
        #pragma unroll
        for (int u2 = 0; u2 < 4; ++u2) {
            u32 o = order_f32(vv[u2]);
            u32 bk = o >> 22;
            if (bk >= B) {
                u32 pos = atomicAdd(&cur[bk], 1u);
                if (pos < NCAND)
                    cand[pos] = ((u64)o << 32) |
                                (u64)(0xFFFFFFFFu - (u32)(4*i + u2));
            }
        }
    }
    __syncthreads();
    rank_and_write(cand, hist, cur, B, 22, 0u, t, b, BX, sx, sy, out);
}

__global__ __launch_bounds__(256) void select_kernel(
    const float* __restrict__ logits,
    const float* __restrict__ boxes,
    const int*   __restrict__ osz,
    const u32*   __restrict__ gcnt,
    const u64*   __restrict__ gbuf,
    float*       __restrict__ out)
{
    __shared__ u64 cand[NCAND];   // 30 KB
    __shared__ u32 hist[NBK];     // 4 KB
    __shared__ u32 cur[NBK];      // 4 KB
    __shared__ u32 csum[64];
    __shared__ u32 scc[NSEG];
    __shared__ int s_B;

    const int b = blockIdx.x;
    const int t = threadIdx.x;
    const u64* __restrict__ gb = gbuf + (size_t)b * NCAND;

    if (t < NSEG) scc[t] = gcnt[b * NSEG + t];
    if (t == 0) s_B = -1;
    for (int i = t; i < NBK; i += 256) { hist[i] = 0; cur[i] = 0; }
    __syncthreads();

    bool fast = true;
    int total = 0;
    #pragma unroll
    for (int k = 0; k < NSEG; ++k) {
        u32 x = scc[k];
        if (x > SEGC) fast = false; else total += (int)x;
    }
    fast = fast && (total >= K_TOP);

    const float sx = (float)osz[1];   // scale = [W, H, W, H]
    const float sy = (float)osz[0];
    const float4* BX = (const float4*)(boxes + (size_t)b * 4000);

    if (fast) {
        // histogram candidates into 1024 biased buckets (o>>20 in [3072,4095])
        for (int i = t; i < NCAND; i += 256) {
            const int k = i / SEGC;            // magic mul
            const int j = i - k * SEGC;
            if (j < (int)scc[k])
                atomicAdd(&hist[(u32)(gb[i] >> 52) - 3072u], 1u);
        }
        __syncthreads();
        scan_buckets(hist, cur, csum, &s_B, t);
        __syncthreads();
        fast = (s_B >= 1);   // B must be strictly above GTHR's partial bucket
    }

    if (fast) {
        const u32 B = (u32)s_B;
        for (int i = t; i < NCAND; i += 256) {   // scatter bucket-grouped
            const int k = i / SEGC;
            const int j = i - k * SEGC;
            if (j < (int)scc[k]) {
                u64 key = gb[i];
                u32 pos = atomicAdd(&cur[(u32)(key >> 52) - 3072u], 1u);
                cand[pos] = key;   // pos < total <= NCAND guaranteed
            }
        }
        __syncthreads();
        rank_and_write(cand, hist, cur, B, 20, 3072u, t, b, BX, sx, sy, out);
    } else {
        full_fallback(logits, b, t, cand, hist, cur, csum, &s_B, BX, sx, sy, out);
    }
}

// no-workspace path: pure per-batch two-pass select
__global__ __launch_bounds__(256) void select_nows_kernel(
    const float* __restrict__ logits,
    const float* __restrict__ boxes,
    const int*   __restrict__ osz,
    float*       __restrict__ out)
{
    __shared__ u64 cand[NCAND];
    __shared__ u32 hist[NBK];
    __shared__ u32 cur[NBK];
    __shared__ u32 csum[64];
    __shared__ int s_B;
    const int b = blockIdx.x;
    const int t = threadIdx.x;
    const float sx = (float)osz[1];
    const float sy = (float)osz[0];
    const float4* BX = (const float4*)(boxes + (size_t)b * 4000);
    full_fallback(logits, b, t, cand, hist, cur, csum, &s_B, BX, sx, sy, out);
}

extern "C" void kernel_launch(void* const* d_in, const int* in_sizes, int n_in,
                              void* d_out, int out_size, void* d_ws, size_t ws_size,
                              hipStream_t stream) {
    const float* logits = (const float*)d_in[0];
    const float* boxes  = (const float*)d_in[1];
    const int*   osz    = (const int*)d_in[2];
    float* out = (float*)d_out;

    const size_t need = 65536 + (size_t)NB * NCAND * sizeof(u64);   // ~7.9 MB
    if (ws_size >= need) {
        u32* gcnt = (u32*)d_ws;                          // NB*NSEG u32 = 40 KB
        u64* gbuf = (u64*)((char*)d_ws + 65536);
        collect_kernel<<<dim3(NB * BPB), dim3(256), 0, stream>>>(logits, gcnt, gbuf);
        select_kernel<<<dim3(NB), dim3(256), 0, stream>>>(logits, boxes, osz,
                                                          gcnt, gbuf, out);
    } else {
        select_nows_kernel<<<dim3(NB), dim3(256), 0, stream>>>(logits, boxes, osz, out);
    }
}

// Round 11
// 33.287 us; speedup vs baseline: 11.9444x; 1.8879x over previous
//
#include <hip/hip_runtime.h>

#define K_TOP  300
#define NCLS   80
#define NB     256
#define NF4    20000       // float4 per batch (80000 floats)
#define GTHR   2.2f        // static collect threshold; rank-300 sits at z~2.67
#define BPB    10          // collect blocks (chunks) per batch
#define CHUNK  2048        // float4 per chunk (last chunk ragged: 1568)
#define WPB    4           // waves per collect block
#define SEGC   96          // per-wave segment capacity (expect ~28.4 +/- 5.3)
#define NSEG   (BPB*WPB)   // 40 segments per batch
#define NCAND  (NSEG*SEGC) // 3840 per batch
#define NBK    1024        // bucket count (fast: o>>20 - 3072; fallback: o>>22)

typedef unsigned int       u32;
typedef unsigned long long u64;

__device__ __forceinline__ u32 order_f32(float f) {
    u32 u = __float_as_uint(f);
    return u ^ ((u >> 31) ? 0xFFFFFFFFu : 0x80000000u);
}
__device__ __forceinline__ float unorder_f32(u32 u) {
    u32 v = (u & 0x80000000u) ? (u ^ 0x80000000u) : ~u;
    return __uint_as_float(v);
}

// ---------------- kernel A: pure-stream collect, per-wave private segments ----
// ballot-aggregated: wave-uniform cursor (SGPR), no LDS, no barriers, no atomics
__device__ __forceinline__ u32 wstore(float v, int idx, u64* __restrict__ seg,
                                      u32 cursor, int lane) {
    const bool win = (v >= GTHR);
    const u64 mask = __ballot(win);
    if (mask) {
        if (win) {
            u32 pos = cursor + (u32)__popcll(mask & ((1ull << lane) - 1ull));
            if (pos < SEGC) {
                u32 o = order_f32(v);
                seg[pos] = ((u64)o << 32) | (u64)(0xFFFFFFFFu - (u32)idx);
            }
        }
        cursor += (u32)__popcll(mask);
    }
    return cursor;
}

__global__ __launch_bounds__(256) void collect_kernel(
    const float* __restrict__ logits,
    u32* __restrict__ gcnt,
    u64* __restrict__ gbuf)
{
    const int blk  = blockIdx.x;
    const int b    = blk / BPB;            // const div -> magic mul
    const int c    = blk - b * BPB;
    const int t    = threadIdx.x;
    const int lane = t & 63;
    const int wseg = blk * WPB + (t >> 6); // global wave-segment id

    const float4* __restrict__ L4 = (const float4*)(logits + (size_t)b * (NF4 * 4));
    const int base4 = c * CHUNK;

    // 8 independent loads in flight; only the last chunk is ragged
    float4 v[8];
    if (c < BPB - 1) {
        #pragma unroll
        for (int j = 0; j < 8; ++j) v[j] = L4[base4 + j * 256 + t];
    } else {
        #pragma unroll
        for (int j = 0; j < 8; ++j) {
            const int idx = base4 + j * 256 + t;
            v[j] = (idx < NF4) ? L4[idx]
                               : make_float4(-1e30f, -1e30f, -1e30f, -1e30f);
        }
    }

    u64* __restrict__ seg = gbuf + (size_t)wseg * SEGC;
    u32 cursor = 0;
    #pragma unroll
    for (int j = 0; j < 8; ++j) {
        const int i4 = (base4 + j * 256 + t) * 4;
        cursor = wstore(v[j].x, i4 + 0, seg, cursor, lane);
        cursor = wstore(v[j].y, i4 + 1, seg, cursor, lane);
        cursor = wstore(v[j].z, i4 + 2, seg, cursor, lane);
        cursor = wstore(v[j].w, i4 + 3, seg, cursor, lane);
    }
    if (lane == 0) gcnt[wseg] = cursor;    // > SEGC signals overflow -> fallback
}

// ---------------- kernel B: per-batch select / rank / write (1024 threads) ----

// Fully parallel exclusive-suffix scan over NBK=1024 buckets, 1024 threads,
// one bucket per thread, shfl-based (no serial loops, no cross-thread hist
// reads). On return hist[t]=cur[t]=ex (count of keys in buckets > t),
// *s_B = max t with suffix(>=t) >= K_TOP. Caller barriers before/after.
__device__ __forceinline__ void scan1024(u32* hist, u32* cur, u32* wsum,
                                         int* s_B, int t) {
    const int lane = t & 63, w = t >> 6;
    const u32 h = hist[t];
    u32 s = h;
    #pragma unroll
    for (int off = 1; off < 64; off <<= 1) {   // inclusive suffix within wave
        u32 v = (u32)__shfl_down((int)s, off);
        if (lane + off < 64) s += v;
    }
    if (lane == 0) wsum[w] = s;                // wave total
    __syncthreads();
    u32 wexc = 0;
    #pragma unroll
    for (int j = 0; j < 16; ++j)               // suffix over wave totals
        if (j > w) wexc += wsum[j];
    const u32 incl = s + wexc;                 // count of keys in buckets >= t
    const u32 ex   = incl - h;
    if (incl >= K_TOP) atomicMax(s_B, t);      // non-increasing in t -> max wins
    hist[t] = ex;
    cur[t]  = ex;
}

__device__ __forceinline__ void write_row(float* __restrict__ out, int b, int rank,
                                          u64 key, const float4* __restrict__ BX,
                                          float sx, float sy) {
    u32 o   = (u32)(key >> 32);
    u32 idx = ~((u32)key);
    float logit = unorder_f32(o);
    float score = 1.0f / (1.0f + expf(-logit));
    int label = (int)(idx % NCLS);
    int q     = (int)(idx / NCLS);
    float4 bx = BX[q];
    float* po = out + ((size_t)b * K_TOP + rank) * 6;
    po[0] = (float)label;
    po[1] = score;
    po[2] = (bx.x - 0.5f * bx.z) * sx;
    po[3] = (bx.y - 0.5f * bx.w) * sy;
    po[4] = bx.z * sx;
    po[5] = bx.w * sy;
}

// rank within own bucket segment (cand bucket-grouped); write top-300.
// bucket(key) = (key >> (32+shift)) - bias. 1024-thread strides.
__device__ __forceinline__ void rank_and_write(const u64* cand, const u32* hist,
                                               const u32* cur, u32 B, int shift,
                                               u32 bias, int t, int b,
                                               const float4* BX, float sx, float sy,
                                               float* out) {
    int total = (int)cur[B]; if (total > NCAND) total = NCAND;
    for (int i = t; i < total; i += 1024) {
        u64 key = cand[i];
        u32 bk   = (u32)(key >> (32 + shift)) - bias;
        int segS = (int)hist[bk];
        int segE = (int)cur[bk]; if (segE > NCAND) segE = NCAND;
        int r = segS;
        int j = segS;
        for (; j + 3 < segE; j += 4) {         // unrolled: pipeline ds_reads
            u64 c0 = cand[j], c1 = cand[j+1], c2 = cand[j+2], c3 = cand[j+3];
            r += (c0 > key) ? 1 : 0;
            r += (c1 > key) ? 1 : 0;
            r += (c2 > key) ? 1 : 0;
            r += (c3 > key) ? 1 : 0;
        }
        for (; j < segE; ++j)
            r += (cand[j] > key) ? 1 : 0;
        if (r < K_TOP)
            write_row(out, b, r, key, BX, sx, sy);
    }
}

// full two-pass fallback for batch b (degenerate data / no workspace)
__device__ void full_fallback(const float* __restrict__ logits, int b, int t,
                              u64* cand, u32* hist, u32* cur, u32* wsum, int* s_B,
                              const float4* BX, float sx, float sy,
                              float* __restrict__ out) {
    __syncthreads();
    hist[t] = 0; cur[t] = 0;                   // t spans exactly NBK
    if (t == 0) *s_B = -1;
    __syncthreads();
    const float4* L4 = (const float4*)(logits + (size_t)b * (NF4 * 4));
    for (int i = t; i < NF4; i += 1024) {
        float4 v = L4[i];
        atomicAdd(&hist[order_f32(v.x) >> 22], 1u);
        atomicAdd(&hist[order_f32(v.y) >> 22], 1u);
        atomicAdd(&hist[order_f32(v.z) >> 22], 1u);
        atomicAdd(&hist[order_f32(v.w) >> 22], 1u);
    }
    __syncthreads();
    scan1024(hist, cur, wsum, s_B, t);
    __syncthreads();
    const u32 B = (u32)*s_B;
    for (int i = t; i < NF4; i += 1024) {
        float4 v = L4[i];
        float vv[4] = {v.x, v.y, v.z, v.w};
        #pragma unroll
        for (int u2 = 0; u2 < 4; ++u2) {
            u32 o = order_f32(vv[u2]);
            u32 bk = o >> 22;
            if (bk >= B) {
                u32 pos = atomicAdd(&cur[bk], 1u);
                if (pos < NCAND)
                    cand[pos] = ((u64)o << 32) |
                                (u64)(0xFFFFFFFFu - (u32)(4*i + u2));
            }
        }
    }
    __syncthreads();
    rank_and_write(cand, hist, cur, B, 22, 0u, t, b, BX, sx, sy, out);
}

__global__ __launch_bounds__(1024) void select_kernel(
    const float* __restrict__ logits,
    const float* __restrict__ boxes,
    const int*   __restrict__ osz,
    const u32*   __restrict__ gcnt,
    const u64*   __restrict__ gbuf,
    float*       __restrict__ out)
{
    __shared__ u64 cand[NCAND];   // 30 KB
    __shared__ u32 hist[NBK];     // 4 KB
    __shared__ u32 cur[NBK];      // 4 KB
    __shared__ u32 wsum[16];
    __shared__ u32 scc[NSEG];
    __shared__ int s_B;

    const int b = blockIdx.x;
    const int t = threadIdx.x;
    const u64* __restrict__ gb = gbuf + (size_t)b * NCAND;

    if (t < NSEG) scc[t] = gcnt[b * NSEG + t];
    if (t == 0) s_B = -1;
    hist[t] = 0;                  // t spans exactly NBK
    cur[t]  = 0;
    __syncthreads();

    bool fast = true;
    int total = 0;
    #pragma unroll
    for (int k = 0; k < NSEG; ++k) {
        u32 x = scc[k];
        if (x > SEGC) fast = false; else total += (int)x;
    }
    fast = fast && (total >= K_TOP);

    const float sx = (float)osz[1];   // scale = [W, H, W, H]
    const float sy = (float)osz[0];
    const float4* BX = (const float4*)(boxes + (size_t)b * 4000);

    if (fast) {
        // histogram into 1024 biased buckets. Loads UNconditional (hoistable);
        // only the atomic is guarded by slot validity.
        #pragma unroll
        for (int i = t; i < NCAND; i += 1024) {
            u64 key = gb[i];
            const int k = i / SEGC;            // magic mul
            const int j = i - k * SEGC;
            if (j < (int)scc[k])
                atomicAdd(&hist[(u32)(key >> 52) - 3072u], 1u);
        }
        __syncthreads();
        scan1024(hist, cur, wsum, &s_B, t);
        __syncthreads();
        fast = (s_B >= 1);   // B must be strictly above GTHR's partial bucket
    }

    if (fast) {
        const u32 B = (u32)s_B;
        #pragma unroll
        for (int i = t; i < NCAND; i += 1024) {   // scatter bucket-grouped
            u64 key = gb[i];
            const int k = i / SEGC;
            const int j = i - k * SEGC;
            if (j < (int)scc[k]) {
                u32 pos = atomicAdd(&cur[(u32)(key >> 52) - 3072u], 1u);
                cand[pos] = key;   // pos < total <= NCAND guaranteed
            }
        }
        __syncthreads();
        rank_and_write(cand, hist, cur, B, 20, 3072u, t, b, BX, sx, sy, out);
    } else {
        full_fallback(logits, b, t, cand, hist, cur, wsum, &s_B, BX, sx, sy, out);
    }
}

// no-workspace path: pure per-batch two-pass select
__global__ __launch_bounds__(1024) void select_nows_kernel(
    const float* __restrict__ logits,
    const float* __restrict__ boxes,
    const int*   __restrict__ osz,
    float*       __restrict__ out)
{
    __shared__ u64 cand[NCAND];
    __shared__ u32 hist[NBK];
    __shared__ u32 cur[NBK];
    __shared__ u32 wsum[16];
    __shared__ int s_B;
    const int b = blockIdx.x;
    const int t = threadIdx.x;
    const float sx = (float)osz[1];
    const float sy = (float)osz[0];
    const float4* BX = (const float4*)(boxes + (size_t)b * 4000);
    full_fallback(logits, b, t, cand, hist, cur, wsum, &s_B, BX, sx, sy, out);
}

extern "C" void kernel_launch(void* const* d_in, const int* in_sizes, int n_in,
                              void* d_out, int out_size, void* d_ws, size_t ws_size,
                              hipStream_t stream) {
    const float* logits = (const float*)d_in[0];
    const float* boxes  = (const float*)d_in[1];
    const int*   osz    = (const int*)d_in[2];
    float* out = (float*)d_out;

    const size_t need = 65536 + (size_t)NB * NCAND * sizeof(u64);   // ~7.9 MB
    if (ws_size >= need) {
        u32* gcnt = (u32*)d_ws;                          // NB*NSEG u32 = 40 KB
        u64* gbuf = (u64*)((char*)d_ws + 65536);
        collect_kernel<<<dim3(NB * BPB), dim3(256), 0, stream>>>(logits, gcnt, gbuf);
        select_kernel<<<dim3(NB), dim3(1024), 0, stream>>>(logits, boxes, osz,
                                                           gcnt, gbuf, out);
    } else {
        select_nows_kernel<<<dim3(NB), dim3(1024), 0, stream>>>(logits, boxes, osz, out);
    }
}

// Round 12
// 32.706 us; speedup vs baseline: 12.1565x; 1.0178x over previous
//
#include <hip/hip_runtime.h>

#define K_TOP  300
#define NCLS   80
#define NB     256
#define NF4    20000       // float4 per batch (80000 floats)
#define GTHR   2.2f        // static collect threshold; rank-300 sits at z~2.67
#define BPB    10          // collect blocks (chunks) per batch
#define CHUNK  2048        // float4 per chunk (last chunk ragged: 1568)
#define WPB    4           // waves per collect block
#define SEGC   96          // per-wave segment capacity (expect ~28.4 +/- 5.3)
#define NSEG   (BPB*WPB)   // 40 segments per batch
#define NCAND  (NSEG*SEGC) // 3840 per batch
#define NBK    1024        // bucket count (fast: o>>20 - 3072; fallback: o>>22)

typedef unsigned int       u32;
typedef unsigned long long u64;

__device__ __forceinline__ u32 order_f32(float f) {
    u32 u = __float_as_uint(f);
    return u ^ ((u >> 31) ? 0xFFFFFFFFu : 0x80000000u);
}
__device__ __forceinline__ float unorder_f32(u32 u) {
    u32 v = (u & 0x80000000u) ? (u ^ 0x80000000u) : ~u;
    return __uint_as_float(v);
}

// ---------------- kernel A: pure-stream collect, per-wave private segments ----
// ballot-aggregated: wave-uniform cursor (SGPR), no LDS, no barriers, no atomics
__device__ __forceinline__ u32 wstore(float v, int idx, u64* __restrict__ seg,
                                      u32 cursor, int lane) {
    const bool win = (v >= GTHR);
    const u64 mask = __ballot(win);
    if (mask) {
        if (win) {
            u32 pos = cursor + (u32)__popcll(mask & ((1ull << lane) - 1ull));
            if (pos < SEGC) {
                u32 o = order_f32(v);
                seg[pos] = ((u64)o << 32) | (u64)(0xFFFFFFFFu - (u32)idx);
            }
        }
        cursor += (u32)__popcll(mask);
    }
    return cursor;
}

__global__ __launch_bounds__(256) void collect_kernel(
    const float* __restrict__ logits,
    u32* __restrict__ gcnt,
    u64* __restrict__ gbuf)
{
    const int blk  = blockIdx.x;
    const int b    = blk / BPB;            // const div -> magic mul
    const int c    = blk - b * BPB;
    const int t    = threadIdx.x;
    const int lane = t & 63;
    const int wseg = blk * WPB + (t >> 6); // global wave-segment id

    const float4* __restrict__ L4 = (const float4*)(logits + (size_t)b * (NF4 * 4));
    const int base4 = c * CHUNK;

    // 8 independent loads in flight; only the last chunk is ragged
    float4 v[8];
    if (c < BPB - 1) {
        #pragma unroll
        for (int j = 0; j < 8; ++j) v[j] = L4[base4 + j * 256 + t];
    } else {
        #pragma unroll
        for (int j = 0; j < 8; ++j) {
            const int idx = base4 + j * 256 + t;
            v[j] = (idx < NF4) ? L4[idx]
                               : make_float4(-1e30f, -1e30f, -1e30f, -1e30f);
        }
    }

    u64* __restrict__ seg = gbuf + (size_t)wseg * SEGC;
    u32 cursor = 0;
    #pragma unroll
    for (int j = 0; j < 8; ++j) {
        const int i4 = (base4 + j * 256 + t) * 4;
        cursor = wstore(v[j].x, i4 + 0, seg, cursor, lane);
        cursor = wstore(v[j].y, i4 + 1, seg, cursor, lane);
        cursor = wstore(v[j].z, i4 + 2, seg, cursor, lane);
        cursor = wstore(v[j].w, i4 + 3, seg, cursor, lane);
    }
    if (lane == 0) gcnt[wseg] = cursor;    // > SEGC signals overflow -> fallback
}

// ---------------- kernel B: per-batch select / rank / write (1024 threads) ----

// Fully parallel exclusive-suffix scan over NBK=1024 buckets, 1024 threads,
// one bucket per thread, shfl-based. On return hist[t]=cur[t]=ex (count of
// keys in buckets > t), *s_B = max t with suffix(>=t) >= K_TOP.
// Caller barriers before/after.
__device__ __forceinline__ void scan1024(u32* hist, u32* cur, u32* wsum,
                                         int* s_B, int t) {
    const int lane = t & 63, w = t >> 6;
    const u32 h = hist[t];
    u32 s = h;
    #pragma unroll
    for (int off = 1; off < 64; off <<= 1) {   // inclusive suffix within wave
        u32 v = (u32)__shfl_down((int)s, off);
        if (lane + off < 64) s += v;
    }
    if (lane == 0) wsum[w] = s;                // wave total
    __syncthreads();
    u32 wexc = 0;
    #pragma unroll
    for (int j = 0; j < 16; ++j)               // suffix over wave totals
        if (j > w) wexc += wsum[j];
    const u32 incl = s + wexc;                 // count of keys in buckets >= t
    const u32 ex   = incl - h;
    if (incl >= K_TOP) atomicMax(s_B, t);      // non-increasing in t -> max wins
    hist[t] = ex;
    cur[t]  = ex;
}

__device__ __forceinline__ void write_row(float* __restrict__ out, int b, int rank,
                                          u64 key, const float4* __restrict__ BX,
                                          float sx, float sy) {
    u32 o   = (u32)(key >> 32);
    u32 idx = ~((u32)key);
    float logit = unorder_f32(o);
    float score = 1.0f / (1.0f + expf(-logit));
    int label = (int)(idx % NCLS);
    int q     = (int)(idx / NCLS);
    float4 bx = BX[q];
    float* po = out + ((size_t)b * K_TOP + rank) * 6;
    po[0] = (float)label;
    po[1] = score;
    po[2] = (bx.x - 0.5f * bx.z) * sx;
    po[3] = (bx.y - 0.5f * bx.w) * sy;
    po[4] = bx.z * sx;
    po[5] = bx.w * sy;
}

// rank within own bucket segment (cand bucket-grouped); write top-300.
// bucket(key) = (key >> (32+shift)) - bias. 1024-thread strides.
__device__ __forceinline__ void rank_and_write(const u64* cand, const u32* hist,
                                               const u32* cur, u32 B, int shift,
                                               u32 bias, int t, int b,
                                               const float4* BX, float sx, float sy,
                                               float* out) {
    int total = (int)cur[B]; if (total > NCAND) total = NCAND;
    for (int i = t; i < total; i += 1024) {
        u64 key = cand[i];
        u32 bk   = (u32)(key >> (32 + shift)) - bias;
        int segS = (int)hist[bk];
        int segE = (int)cur[bk]; if (segE > NCAND) segE = NCAND;
        int r = segS;
        int j = segS;
        for (; j + 3 < segE; j += 4) {         // unrolled: pipeline ds_reads
            u64 c0 = cand[j], c1 = cand[j+1], c2 = cand[j+2], c3 = cand[j+3];
            r += (c0 > key) ? 1 : 0;
            r += (c1 > key) ? 1 : 0;
            r += (c2 > key) ? 1 : 0;
            r += (c3 > key) ? 1 : 0;
        }
        for (; j < segE; ++j)
            r += (cand[j] > key) ? 1 : 0;
        if (r < K_TOP)
            write_row(out, b, r, key, BX, sx, sy);
    }
}

// full two-pass fallback for batch b (degenerate data / no workspace)
__device__ void full_fallback(const float* __restrict__ logits, int b, int t,
                              u64* cand, u32* hist, u32* cur, u32* wsum, int* s_B,
                              const float4* BX, float sx, float sy,
                              float* __restrict__ out) {
    __syncthreads();
    hist[t] = 0; cur[t] = 0;                   // t spans exactly NBK
    if (t == 0) *s_B = -1;
    __syncthreads();
    const float4* L4 = (const float4*)(logits + (size_t)b * (NF4 * 4));
    for (int i = t; i < NF4; i += 1024) {
        float4 v = L4[i];
        atomicAdd(&hist[order_f32(v.x) >> 22], 1u);
        atomicAdd(&hist[order_f32(v.y) >> 22], 1u);
        atomicAdd(&hist[order_f32(v.z) >> 22], 1u);
        atomicAdd(&hist[order_f32(v.w) >> 22], 1u);
    }
    __syncthreads();
    scan1024(hist, cur, wsum, s_B, t);
    __syncthreads();
    const u32 B = (u32)*s_B;
    for (int i = t; i < NF4; i += 1024) {
        float4 v = L4[i];
        float vv[4] = {v.x, v.y, v.z, v.w};
        #pragma unroll
        for (int u2 = 0; u2 < 4; ++u2) {
            u32 o = order_f32(vv[u2]);
            u32 bk = o >> 22;
            if (bk >= B) {
                u32 pos = atomicAdd(&cur[bk], 1u);
                if (pos < NCAND)
                    cand[pos] = ((u64)o << 32) |
                                (u64)(0xFFFFFFFFu - (u32)(4*i + u2));
            }
        }
    }
    __syncthreads();
    rank_and_write(cand, hist, cur, B, 22, 0u, t, b, BX, sx, sy, out);
}

__global__ __launch_bounds__(1024) void select_kernel(
    const float* __restrict__ logits,
    const float* __restrict__ boxes,
    const int*   __restrict__ osz,
    const u32*   __restrict__ gcnt,
    const u64*   __restrict__ gbuf,
    float*       __restrict__ out)
{
    __shared__ u64 cand[NCAND];   // 30 KB
    __shared__ u32 hist[NBK];     // 4 KB
    __shared__ u32 cur[NBK];      // 4 KB
    __shared__ u32 wsum[16];
    __shared__ u32 scc[NSEG];
    __shared__ int s_B;

    const int b = blockIdx.x;
    const int t = threadIdx.x;
    const u64* __restrict__ gb = gbuf + (size_t)b * NCAND;

    if (t < NSEG) scc[t] = gcnt[b * NSEG + t];
    if (t == 0) s_B = -1;
    hist[t] = 0;                  // t spans exactly NBK
    cur[t]  = 0;
    __syncthreads();

    // ---- single vectorized global read: each thread owns <=4 keys in regs.
    //      NCAND = 3840 u64 = 1920 ulonglong2: pair t (t<1920 via t and t+1024<1920)
    u64 k0 = 0, k1 = 0, k2 = 0, k3 = 0;
    bool v0 = false, v1 = false, v2 = false, v3 = false;
    {
        const ulonglong2* __restrict__ G2 = (const ulonglong2*)gb;
        ulonglong2 p0 = G2[t];                       // slots 2t, 2t+1
        int s0 = 2 * t;
        int seg0 = s0 / SEGC;                        // magic mul
        int j0   = s0 - seg0 * SEGC;
        k0 = p0.x; k1 = p0.y;
        v0 = (j0     < (int)scc[seg0]);
        v1 = (j0 + 1 < (int)scc[seg0]);              // 2t,2t+1 same segment (SEGC even)
        if (t < 896) {                               // pairs 1024..1919
            ulonglong2 p1 = G2[t + 1024];            // slots 2048+2t, 2049+2t
            int s2 = 2048 + 2 * t;
            int seg2 = s2 / SEGC;
            int j2   = s2 - seg2 * SEGC;
            k2 = p1.x; k3 = p1.y;
            v2 = (j2     < (int)scc[seg2]);
            v3 = (j2 + 1 < (int)scc[seg2]);
        }
    }

    bool fast = true;
    int total = 0;
    #pragma unroll
    for (int k = 0; k < NSEG; ++k) {
        u32 x = scc[k];
        if (x > SEGC) fast = false; else total += (int)x;
    }
    fast = fast && (total >= K_TOP);

    const float sx = (float)osz[1];   // scale = [W, H, W, H]
    const float sy = (float)osz[0];
    const float4* BX = (const float4*)(boxes + (size_t)b * 4000);

    if (fast) {
        // histogram from registers into 1024 biased buckets (o>>20 in [3072,4095])
        if (v0) atomicAdd(&hist[(u32)(k0 >> 52) - 3072u], 1u);
        if (v1) atomicAdd(&hist[(u32)(k1 >> 52) - 3072u], 1u);
        if (v2) atomicAdd(&hist[(u32)(k2 >> 52) - 3072u], 1u);
        if (v3) atomicAdd(&hist[(u32)(k3 >> 52) - 3072u], 1u);
        __syncthreads();
        scan1024(hist, cur, wsum, &s_B, t);
        __syncthreads();
        fast = (s_B >= 1);   // B must be strictly above GTHR's partial bucket
    }

    if (fast) {
        const u32 B = (u32)s_B;
        // scatter bucket-grouped from registers
        if (v0) { u32 p = atomicAdd(&cur[(u32)(k0 >> 52) - 3072u], 1u); cand[p] = k0; }
        if (v1) { u32 p = atomicAdd(&cur[(u32)(k1 >> 52) - 3072u], 1u); cand[p] = k1; }
        if (v2) { u32 p = atomicAdd(&cur[(u32)(k2 >> 52) - 3072u], 1u); cand[p] = k2; }
        if (v3) { u32 p = atomicAdd(&cur[(u32)(k3 >> 52) - 3072u], 1u); cand[p] = k3; }
        __syncthreads();
        rank_and_write(cand, hist, cur, B, 20, 3072u, t, b, BX, sx, sy, out);
    } else {
        full_fallback(logits, b, t, cand, hist, cur, wsum, &s_B, BX, sx, sy, out);
    }
}

// no-workspace path: pure per-batch two-pass select
__global__ __launch_bounds__(1024) void select_nows_kernel(
    const float* __restrict__ logits,
    const float* __restrict__ boxes,
    const int*   __restrict__ osz,
    float*       __restrict__ out)
{
    __shared__ u64 cand[NCAND];
    __shared__ u32 hist[NBK];
    __shared__ u32 cur[NBK];
    __shared__ u32 wsum[16];
    __shared__ int s_B;
    const int b = blockIdx.x;
    const int t = threadIdx.x;
    const float sx = (float)osz[1];
    const float sy = (float)osz[0];
    const float4* BX = (const float4*)(boxes + (size_t)b * 4000);
    full_fallback(logits, b, t, cand, hist, cur, wsum, &s_B, BX, sx, sy, out);
}

extern "C" void kernel_launch(void* const* d_in, const int* in_sizes, int n_in,
                              void* d_out, int out_size, void* d_ws, size_t ws_size,
                              hipStream_t stream) {
    const float* logits = (const float*)d_in[0];
    const float* boxes  = (const float*)d_in[1];
    const int*   osz    = (const int*)d_in[2];
    float* out = (float*)d_out;

    const size_t need = 65536 + (size_t)NB * NCAND * sizeof(u64);   // ~7.9 MB
    if (ws_size >= need) {
        u32* gcnt = (u32*)d_ws;                          // NB*NSEG u32 = 40 KB
        u64* gbuf = (u64*)((char*)d_ws + 65536);
        collect_kernel<<<dim3(NB * BPB), dim3(256), 0, stream>>>(logits, gcnt, gbuf);
        select_kernel<<<dim3(NB), dim3(1024), 0, stream>>>(logits, boxes, osz,
                                                           gcnt, gbuf, out);
    } else {
        select_nows_kernel<<<dim3(NB), dim3(1024), 0, stream>>>(logits, boxes, osz, out);
    }
}

// Round 13
// 32.436 us; speedup vs baseline: 12.2576x; 1.0083x over previous
//
#include <hip/hip_runtime.h>

#define K_TOP  300
#define NCLS   80
#define NB     256
#define NF4    20000       // float4 per batch (80000 floats)
#define GTHR   2.2f        // static collect threshold; rank-300 sits at z~2.67
#define BPB    10          // collect blocks (chunks) per batch
#define CHUNK  2048        // float4 per chunk (last chunk ragged: 1568)
#define WPB    4           // waves per collect block
#define SEGC   96          // per-wave segment capacity (expect ~28.4 +/- 5.3)
#define NSEG   (BPB*WPB)   // 40 segments per batch
#define NCAND  (NSEG*SEGC) // 3840 per batch
#define NBK    1024        // bucket count (fast: o>>20 - 3072; fallback: o>>22)

typedef unsigned int       u32;
typedef unsigned long long u64;

__device__ __forceinline__ u32 order_f32(float f) {
    u32 u = __float_as_uint(f);
    return u ^ ((u >> 31) ? 0xFFFFFFFFu : 0x80000000u);
}
__device__ __forceinline__ float unorder_f32(u32 u) {
    u32 v = (u & 0x80000000u) ? (u ^ 0x80000000u) : ~u;
    return __uint_as_float(v);
}

// ---------------- kernel A: pure-stream collect, per-wave private segments ----
// ballot-aggregated: wave-uniform cursor (SGPR), no LDS, no barriers, no atomics
__device__ __forceinline__ u32 wstore(float v, int idx, u64* __restrict__ seg,
                                      u32 cursor, int lane) {
    const bool win = (v >= GTHR);
    const u64 mask = __ballot(win);
    if (mask) {
        if (win) {
            u32 pos = cursor + (u32)__popcll(mask & ((1ull << lane) - 1ull));
            if (pos < SEGC) {
                u32 o = order_f32(v);
                seg[pos] = ((u64)o << 32) | (u64)(0xFFFFFFFFu - (u32)idx);
            }
        }
        cursor += (u32)__popcll(mask);
    }
    return cursor;
}

__global__ __launch_bounds__(256) void collect_kernel(
    const float* __restrict__ logits,
    u32* __restrict__ gcnt,
    u64* __restrict__ gbuf)
{
    // XCD-aligned decomposition: blk = c*NB + b. Since NB % 8 == 0, block
    // (c,b) lands on XCD b%8 under round-robin dispatch -- the SAME XCD as
    // select block b. gbuf segments stay in the consumer's local L2.
    const int blk  = blockIdx.x;
    const int b    = blk & (NB - 1);       // blk % 256
    const int c    = blk >> 8;             // blk / 256
    const int t    = threadIdx.x;
    const int lane = t & 63;
    const int wseg = (b * BPB + c) * WPB + (t >> 6);  // layout unchanged for select

    const float4* __restrict__ L4 = (const float4*)(logits + (size_t)b * (NF4 * 4));
    const int base4 = c * CHUNK;

    // 8 independent loads in flight; only the last chunk is ragged
    float4 v[8];
    if (c < BPB - 1) {
        #pragma unroll
        for (int j = 0; j < 8; ++j) v[j] = L4[base4 + j * 256 + t];
    } else {
        #pragma unroll
        for (int j = 0; j < 8; ++j) {
            const int idx = base4 + j * 256 + t;
            v[j] = (idx < NF4) ? L4[idx]
                               : make_float4(-1e30f, -1e30f, -1e30f, -1e30f);
        }
    }

    u64* __restrict__ seg = gbuf + (size_t)wseg * SEGC;
    u32 cursor = 0;
    #pragma unroll
    for (int j = 0; j < 8; ++j) {
        const int i4 = (base4 + j * 256 + t) * 4;
        cursor = wstore(v[j].x, i4 + 0, seg, cursor, lane);
        cursor = wstore(v[j].y, i4 + 1, seg, cursor, lane);
        cursor = wstore(v[j].z, i4 + 2, seg, cursor, lane);
        cursor = wstore(v[j].w, i4 + 3, seg, cursor, lane);
    }
    if (lane == 0) gcnt[wseg] = cursor;    // > SEGC signals overflow -> fallback
}

// ---------------- kernel B: per-batch select / rank / write (1024 threads) ----

// Fully parallel exclusive-suffix scan over NBK=1024 buckets, 1024 threads,
// one bucket per thread, shfl-based. On return hist[t]=cur[t]=ex (count of
// keys in buckets > t), *s_B = max t with suffix(>=t) >= K_TOP.
// Caller barriers before/after.
__device__ __forceinline__ void scan1024(u32* hist, u32* cur, u32* wsum,
                                         int* s_B, int t) {
    const int lane = t & 63, w = t >> 6;
    const u32 h = hist[t];
    u32 s = h;
    #pragma unroll
    for (int off = 1; off < 64; off <<= 1) {   // inclusive suffix within wave
        u32 v = (u32)__shfl_down((int)s, off);
        if (lane + off < 64) s += v;
    }
    if (lane == 0) wsum[w] = s;                // wave total
    __syncthreads();
    u32 wexc = 0;
    #pragma unroll
    for (int j = 0; j < 16; ++j)               // suffix over wave totals
        if (j > w) wexc += wsum[j];
    const u32 incl = s + wexc;                 // count of keys in buckets >= t
    const u32 ex   = incl - h;
    if (incl >= K_TOP) atomicMax(s_B, t);      // non-increasing in t -> max wins
    hist[t] = ex;
    cur[t]  = ex;
}

__device__ __forceinline__ void write_row(float* __restrict__ out, int b, int rank,
                                          u64 key, const float4* __restrict__ BX,
                                          float sx, float sy) {
    u32 o   = (u32)(key >> 32);
    u32 idx = ~((u32)key);
    float logit = unorder_f32(o);
    float score = 1.0f / (1.0f + expf(-logit));
    int label = (int)(idx % NCLS);
    int q     = (int)(idx / NCLS);
    float4 bx = BX[q];
    float* po = out + ((size_t)b * K_TOP + rank) * 6;
    po[0] = (float)label;
    po[1] = score;
    po[2] = (bx.x - 0.5f * bx.z) * sx;
    po[3] = (bx.y - 0.5f * bx.w) * sy;
    po[4] = bx.z * sx;
    po[5] = bx.w * sy;
}

// rank within own bucket segment (cand bucket-grouped); write top-300.
// bucket(key) = (key >> (32+shift)) - bias. 1024-thread strides.
__device__ __forceinline__ void rank_and_write(const u64* cand, const u32* hist,
                                               const u32* cur, u32 B, int shift,
                                               u32 bias, int t, int b,
                                               const float4* BX, float sx, float sy,
                                               float* out) {
    int total = (int)cur[B]; if (total > NCAND) total = NCAND;
    for (int i = t; i < total; i += 1024) {
        u64 key = cand[i];
        u32 bk   = (u32)(key >> (32 + shift)) - bias;
        int segS = (int)hist[bk];
        int segE = (int)cur[bk]; if (segE > NCAND) segE = NCAND;
        int r = segS;
        int j = segS;
        for (; j + 3 < segE; j += 4) {         // unrolled: pipeline ds_reads
            u64 c0 = cand[j], c1 = cand[j+1], c2 = cand[j+2], c3 = cand[j+3];
            r += (c0 > key) ? 1 : 0;
            r += (c1 > key) ? 1 : 0;
            r += (c2 > key) ? 1 : 0;
            r += (c3 > key) ? 1 : 0;
        }
        for (; j < segE; ++j)
            r += (cand[j] > key) ? 1 : 0;
        if (r < K_TOP)
            write_row(out, b, r, key, BX, sx, sy);
    }
}

// full two-pass fallback for batch b (degenerate data / no workspace)
__device__ void full_fallback(const float* __restrict__ logits, int b, int t,
                              u64* cand, u32* hist, u32* cur, u32* wsum, int* s_B,
                              const float4* BX, float sx, float sy,
                              float* __restrict__ out) {
    __syncthreads();
    hist[t] = 0; cur[t] = 0;                   // t spans exactly NBK
    if (t == 0) *s_B = -1;
    __syncthreads();
    const float4* L4 = (const float4*)(logits + (size_t)b * (NF4 * 4));
    for (int i = t; i < NF4; i += 1024) {
        float4 v = L4[i];
        atomicAdd(&hist[order_f32(v.x) >> 22], 1u);
        atomicAdd(&hist[order_f32(v.y) >> 22], 1u);
        atomicAdd(&hist[order_f32(v.z) >> 22], 1u);
        atomicAdd(&hist[order_f32(v.w) >> 22], 1u);
    }
    __syncthreads();
    scan1024(hist, cur, wsum, s_B, t);
    __syncthreads();
    const u32 B = (u32)*s_B;
    for (int i = t; i < NF4; i += 1024) {
        float4 v = L4[i];
        float vv[4] = {v.x, v.y, v.z, v.w};
        #pragma unroll
        for (int u2 = 0; u2 < 4; ++u2) {
            u32 o = order_f32(vv[u2]);
            u32 bk = o >> 22;
            if (bk >= B) {
                u32 pos = atomicAdd(&cur[bk], 1u);
                if (pos < NCAND)
                    cand[pos] = ((u64)o << 32) |
                                (u64)(0xFFFFFFFFu - (u32)(4*i + u2));
            }
        }
    }
    __syncthreads();
    rank_and_write(cand, hist, cur, B, 22, 0u, t, b, BX, sx, sy, out);
}

__global__ __launch_bounds__(1024) void select_kernel(
    const float* __restrict__ logits,
    const float* __restrict__ boxes,
    const int*   __restrict__ osz,
    const u32*   __restrict__ gcnt,
    const u64*   __restrict__ gbuf,
    float*       __restrict__ out)
{
    __shared__ u64 cand[NCAND];   // 30 KB
    __shared__ u32 hist[NBK];     // 4 KB
    __shared__ u32 cur[NBK];      // 4 KB
    __shared__ u32 wsum[16];
    __shared__ u32 scc[NSEG];
    __shared__ int s_B;

    const int b = blockIdx.x;
    const int t = threadIdx.x;
    const u64* __restrict__ gb = gbuf + (size_t)b * NCAND;

    if (t < NSEG) scc[t] = gcnt[b * NSEG + t];
    if (t == 0) s_B = -1;
    hist[t] = 0;                  // t spans exactly NBK
    cur[t]  = 0;
    __syncthreads();

    // ---- single vectorized global read: each thread owns <=4 keys in regs.
    //      NCAND = 3840 u64 = 1920 ulonglong2
    u64 k0 = 0, k1 = 0, k2 = 0, k3 = 0;
    bool v0 = false, v1 = false, v2 = false, v3 = false;
    {
        const ulonglong2* __restrict__ G2 = (const ulonglong2*)gb;
        ulonglong2 p0 = G2[t];                       // slots 2t, 2t+1
        int s0 = 2 * t;
        int seg0 = s0 / SEGC;                        // magic mul
        int j0   = s0 - seg0 * SEGC;
        k0 = p0.x; k1 = p0.y;
        v0 = (j0     < (int)scc[seg0]);
        v1 = (j0 + 1 < (int)scc[seg0]);              // 2t,2t+1 same segment (SEGC even)
        if (t < 896) {                               // pairs 1024..1919
            ulonglong2 p1 = G2[t + 1024];            // slots 2048+2t, 2049+2t
            int s2 = 2048 + 2 * t;
            int seg2 = s2 / SEGC;
            int j2   = s2 - seg2 * SEGC;
            k2 = p1.x; k3 = p1.y;
            v2 = (j2     < (int)scc[seg2]);
            v3 = (j2 + 1 < (int)scc[seg2]);
        }
    }

    bool fast = true;
    int total = 0;
    #pragma unroll
    for (int k = 0; k < NSEG; ++k) {
        u32 x = scc[k];
        if (x > SEGC) fast = false; else total += (int)x;
    }
    fast = fast && (total >= K_TOP);

    const float sx = (float)osz[1];   // scale = [W, H, W, H]
    const float sy = (float)osz[0];
    const float4* BX = (const float4*)(boxes + (size_t)b * 4000);

    if (fast) {
        // histogram from registers into 1024 biased buckets (o>>20 in [3072,4095])
        if (v0) atomicAdd(&hist[(u32)(k0 >> 52) - 3072u], 1u);
        if (v1) atomicAdd(&hist[(u32)(k1 >> 52) - 3072u], 1u);
        if (v2) atomicAdd(&hist[(u32)(k2 >> 52) - 3072u], 1u);
        if (v3) atomicAdd(&hist[(u32)(k3 >> 52) - 3072u], 1u);
        __syncthreads();
        scan1024(hist, cur, wsum, &s_B, t);
        __syncthreads();
        fast = (s_B >= 1);   // B must be strictly above GTHR's partial bucket
    }

    if (fast) {
        const u32 B = (u32)s_B;
        // scatter bucket-grouped from registers
        if (v0) { u32 p = atomicAdd(&cur[(u32)(k0 >> 52) - 3072u], 1u); cand[p] = k0; }
        if (v1) { u32 p = atomicAdd(&cur[(u32)(k1 >> 52) - 3072u], 1u); cand[p] = k1; }
        if (v2) { u32 p = atomicAdd(&cur[(u32)(k2 >> 52) - 3072u], 1u); cand[p] = k2; }
        if (v3) { u32 p = atomicAdd(&cur[(u32)(k3 >> 52) - 3072u], 1u); cand[p] = k3; }
        __syncthreads();
        rank_and_write(cand, hist, cur, B, 20, 3072u, t, b, BX, sx, sy, out);
    } else {
        full_fallback(logits, b, t, cand, hist, cur, wsum, &s_B, BX, sx, sy, out);
    }
}

// no-workspace path: pure per-batch two-pass select
__global__ __launch_bounds__(1024) void select_nows_kernel(
    const float* __restrict__ logits,
    const float* __restrict__ boxes,
    const int*   __restrict__ osz,
    float*       __restrict__ out)
{
    __shared__ u64 cand[NCAND];
    __shared__ u32 hist[NBK];
    __shared__ u32 cur[NBK];
    __shared__ u32 wsum[16];
    __shared__ int s_B;
    const int b = blockIdx.x;
    const int t = threadIdx.x;
    const float sx = (float)osz[1];
    const float sy = (float)osz[0];
    const float4* BX = (const float4*)(boxes + (size_t)b * 4000);
    full_fallback(logits, b, t, cand, hist, cur, wsum, &s_B, BX, sx, sy, out);
}

extern "C" void kernel_launch(void* const* d_in, const int* in_sizes, int n_in,
                              void* d_out, int out_size, void* d_ws, size_t ws_size,
                              hipStream_t stream) {
    const float* logits = (const float*)d_in[0];
    const float* boxes  = (const float*)d_in[1];
    const int*   osz    = (const int*)d_in[2];
    float* out = (float*)d_out;

    const size_t need = 65536 + (size_t)NB * NCAND * sizeof(u64);   // ~7.9 MB
    if (ws_size >= need) {
        u32* gcnt = (u32*)d_ws;                          // NB*NSEG u32 = 40 KB
        u64* gbuf = (u64*)((char*)d_ws + 65536);
        collect_kernel<<<dim3(NB * BPB), dim3(256), 0, stream>>>(logits, gcnt, gbuf);
        select_kernel<<<dim3(NB), dim3(1024), 0, stream>>>(logits, boxes, osz,
                                                           gcnt, gbuf, out);
    } else {
        select_nows_kernel<<<dim3(NB), dim3(1024), 0, stream>>>(logits, boxes, osz, out);
    }
}

// Round 14
// 27.892 us; speedup vs baseline: 14.2546x; 1.1629x over previous
//
#include <hip/hip_runtime.h>

#define K_TOP  300
#define NCLS   80
#define NB     256
#define NF4    20000       // float4 per batch (80000 floats)
#define GTHR   2.2f        // static collect threshold; rank-300 sits at z~2.67
#define BPB    10          // collect blocks (chunks) per batch
#define CHUNK  2048        // float4 per chunk (last chunk ragged: 1568)
#define WPB    4           // waves per collect block
#define SEGC   96          // per-wave segment capacity (expect ~28.4 +/- 5.3)
#define NSEG   (BPB*WPB)   // 40 segments per batch
#define NCAND  (NSEG*SEGC) // 3840 per batch
#define NBK    1024        // bucket count

typedef unsigned int       u32;
typedef unsigned long long u64;

__device__ __forceinline__ u32 order_f32(float f) {
    u32 u = __float_as_uint(f);
    return u ^ ((u >> 31) ? 0xFFFFFFFFu : 0x80000000u);
}
__device__ __forceinline__ float unorder_f32(u32 u) {
    u32 v = (u & 0x80000000u) ? (u ^ 0x80000000u) : ~u;
    return __uint_as_float(v);
}

// fast-path bucket: fine granularity (o>>14), biased at GTHR, clamped.
// Monotone non-decreasing in key; candidates (>= GTHR) map to [0, 1023].
__device__ __forceinline__ u32 fbucket(u64 key, u32 bias14) {
    u32 d = (u32)(key >> 46) - bias14;     // (o >> 14) - bias
    return (d > 1023u) ? 1023u : d;
}

// ---------------- kernel A: pure-stream collect, per-wave private segments ----
// ballot-aggregated: wave-uniform cursor (SGPR), no LDS, no barriers, no atomics
__device__ __forceinline__ u32 wstore(float v, int idx, u64* __restrict__ seg,
                                      u32 cursor, int lane) {
    const bool win = (v >= GTHR);
    const u64 mask = __ballot(win);
    if (mask) {
        if (win) {
            u32 pos = cursor + (u32)__popcll(mask & ((1ull << lane) - 1ull));
            if (pos < SEGC) {
                u32 o = order_f32(v);
                seg[pos] = ((u64)o << 32) | (u64)(0xFFFFFFFFu - (u32)idx);
            }
        }
        cursor += (u32)__popcll(mask);
    }
    return cursor;
}

__global__ __launch_bounds__(256) void collect_kernel(
    const float* __restrict__ logits,
    u32* __restrict__ gcnt,
    u64* __restrict__ gbuf)
{
    // XCD-aligned decomposition: blk = c*NB + b (NB%8==0 -> same XCD as select b)
    const int blk  = blockIdx.x;
    const int b    = blk & (NB - 1);
    const int c    = blk >> 8;
    const int t    = threadIdx.x;
    const int lane = t & 63;
    const int wseg = (b * BPB + c) * WPB + (t >> 6);

    const float4* __restrict__ L4 = (const float4*)(logits + (size_t)b * (NF4 * 4));
    const int base4 = c * CHUNK;

    float4 v[8];
    if (c < BPB - 1) {
        #pragma unroll
        for (int j = 0; j < 8; ++j) v[j] = L4[base4 + j * 256 + t];
    } else {
        #pragma unroll
        for (int j = 0; j < 8; ++j) {
            const int idx = base4 + j * 256 + t;
            v[j] = (idx < NF4) ? L4[idx]
                               : make_float4(-1e30f, -1e30f, -1e30f, -1e30f);
        }
    }

    u64* __restrict__ seg = gbuf + (size_t)wseg * SEGC;
    u32 cursor = 0;
    #pragma unroll
    for (int j = 0; j < 8; ++j) {
        const int i4 = (base4 + j * 256 + t) * 4;
        cursor = wstore(v[j].x, i4 + 0, seg, cursor, lane);
        cursor = wstore(v[j].y, i4 + 1, seg, cursor, lane);
        cursor = wstore(v[j].z, i4 + 2, seg, cursor, lane);
        cursor = wstore(v[j].w, i4 + 3, seg, cursor, lane);
    }
    if (lane == 0) gcnt[wseg] = cursor;    // > SEGC signals overflow -> fallback
}

// ---------------- kernel B: per-batch select / rank / write (1024 threads) ----

// Parallel exclusive-suffix scan over NBK=1024 buckets, 1 bucket/thread.
// On return hist[t]=cur[t]=ex, *s_B = max t with suffix(>=t) >= K_TOP.
__device__ __forceinline__ void scan1024(u32* hist, u32* cur, u32* wsum,
                                         int* s_B, int t) {
    const int lane = t & 63, w = t >> 6;
    const u32 h = hist[t];
    u32 s = h;
    #pragma unroll
    for (int off = 1; off < 64; off <<= 1) {   // inclusive suffix within wave
        u32 v = (u32)__shfl_down((int)s, off);
        if (lane + off < 64) s += v;
    }
    if (lane == 0) wsum[w] = s;
    __syncthreads();
    u32 wexc = 0;
    #pragma unroll
    for (int j = 0; j < 16; ++j)
        if (j > w) wexc += wsum[j];
    const u32 incl = s + wexc;
    const u32 ex   = incl - h;
    if (incl >= K_TOP) atomicMax(s_B, t);
    hist[t] = ex;
    cur[t]  = ex;
}

// rank within own bucket segment (cand bucket-grouped, slots [0,cur[B]) are
// exactly the keys with bucket >= B); write top-300. Box float4 prefetched
// before the rank loop (independent of rank).
__device__ __forceinline__ void rank_and_write(const u64* cand, const u32* hist,
                                               const u32* cur, u32 B, bool fine,
                                               u32 bias14, int t, int b,
                                               const float4* BX, float sx, float sy,
                                               float* out) {
    int total = (int)cur[B]; if (total > NCAND) total = NCAND;
    for (int i = t; i < total; i += 1024) {
        u64 key = cand[i];
        u32 bk  = fine ? fbucket(key, bias14) : (u32)(key >> 54);
        u32 o   = (u32)(key >> 32);
        u32 idx = ~((u32)key);
        int label = (int)(idx % NCLS);
        int q     = (int)(idx / NCLS);
        float4 bx = BX[q];                     // prefetch: hides under rank loop
        int segS = (int)hist[bk];
        int segE = (int)cur[bk]; if (segE > NCAND) segE = NCAND;
        int r = segS;
        for (int j = segS; j < segE; ++j)
            r += (cand[j] > key) ? 1 : 0;
        if (r < K_TOP) {
            float logit = unorder_f32(o);
            float score = 1.0f / (1.0f + expf(-logit));
            float* po = out + ((size_t)b * K_TOP + r) * 6;
            po[0] = (float)label;
            po[1] = score;
            po[2] = (bx.x - 0.5f * bx.z) * sx;
            po[3] = (bx.y - 0.5f * bx.w) * sy;
            po[4] = bx.z * sx;
            po[5] = bx.w * sy;
        }
    }
}

// full two-pass fallback for batch b (degenerate data / no workspace).
// Coarse buckets o>>22 (bias 0), unconditional correctness.
__device__ void full_fallback(const float* __restrict__ logits, int b, int t,
                              u64* cand, u32* hist, u32* cur, u32* wsum, int* s_B,
                              const float4* BX, float sx, float sy,
                              float* __restrict__ out) {
    __syncthreads();
    hist[t] = 0; cur[t] = 0;
    if (t == 0) *s_B = -1;
    __syncthreads();
    const float4* L4 = (const float4*)(logits + (size_t)b * (NF4 * 4));
    for (int i = t; i < NF4; i += 1024) {
        float4 v = L4[i];
        atomicAdd(&hist[order_f32(v.x) >> 22], 1u);
        atomicAdd(&hist[order_f32(v.y) >> 22], 1u);
        atomicAdd(&hist[order_f32(v.z) >> 22], 1u);
        atomicAdd(&hist[order_f32(v.w) >> 22], 1u);
    }
    __syncthreads();
    scan1024(hist, cur, wsum, s_B, t);
    __syncthreads();
    const u32 B = (u32)*s_B;
    for (int i = t; i < NF4; i += 1024) {
        float4 v = L4[i];
        float vv[4] = {v.x, v.y, v.z, v.w};
        #pragma unroll
        for (int u2 = 0; u2 < 4; ++u2) {
            u32 o = order_f32(vv[u2]);
            u32 bk = o >> 22;
            if (bk >= B) {
                u32 pos = atomicAdd(&cur[bk], 1u);
                if (pos < NCAND)
                    cand[pos] = ((u64)o << 32) |
                                (u64)(0xFFFFFFFFu - (u32)(4*i + u2));
            }
        }
    }
    __syncthreads();
    rank_and_write(cand, hist, cur, B, false, 0u, t, b, BX, sx, sy, out);
}

__global__ __launch_bounds__(1024) void select_kernel(
    const float* __restrict__ logits,
    const float* __restrict__ boxes,
    const int*   __restrict__ osz,
    const u32*   __restrict__ gcnt,
    const u64*   __restrict__ gbuf,
    float*       __restrict__ out)
{
    __shared__ u64 cand[NCAND];   // 30 KB
    __shared__ u32 hist[NBK];     // 4 KB
    __shared__ u32 cur[NBK];      // 4 KB
    __shared__ u32 wsum[16];
    __shared__ u32 scc[NSEG];
    __shared__ int s_B;

    const int b = blockIdx.x;
    const int t = threadIdx.x;
    const u64* __restrict__ gb = gbuf + (size_t)b * NCAND;
    const u32 BIAS14 = order_f32(GTHR) >> 14;   // compile-time constant

    if (t < NSEG) scc[t] = gcnt[b * NSEG + t];
    if (t == 0) s_B = -1;
    hist[t] = 0;                  // t spans exactly NBK
    __syncthreads();

    // ---- single vectorized global read: each thread owns <=4 keys in regs ----
    u64 k0 = 0, k1 = 0, k2 = 0, k3 = 0;
    bool v0 = false, v1 = false, v2 = false, v3 = false;
    {
        const ulonglong2* __restrict__ G2 = (const ulonglong2*)gb;
        ulonglong2 p0 = G2[t];                       // slots 2t, 2t+1
        int s0 = 2 * t;
        int seg0 = s0 / SEGC;
        int j0   = s0 - seg0 * SEGC;
        k0 = p0.x; k1 = p0.y;
        v0 = (j0     < (int)scc[seg0]);
        v1 = (j0 + 1 < (int)scc[seg0]);              // same segment (SEGC even)
        if (t < 896) {
            ulonglong2 p1 = G2[t + 1024];
            int s2 = 2048 + 2 * t;
            int seg2 = s2 / SEGC;
            int j2   = s2 - seg2 * SEGC;
            k2 = p1.x; k3 = p1.y;
            v2 = (j2     < (int)scc[seg2]);
            v3 = (j2 + 1 < (int)scc[seg2]);
        }
    }

    bool fast = true;
    int total = 0;
    #pragma unroll
    for (int k = 0; k < NSEG; ++k) {
        u32 x = scc[k];
        if (x > SEGC) fast = false; else total += (int)x;
    }
    fast = fast && (total >= K_TOP);

    const float sx = (float)osz[1];   // scale = [W, H, W, H]
    const float sy = (float)osz[0];
    const float4* BX = (const float4*)(boxes + (size_t)b * 4000);

    if (fast) {
        // fine-bucket histogram from registers (threshold bucket ~7-20 keys)
        if (v0) atomicAdd(&hist[fbucket(k0, BIAS14)], 1u);
        if (v1) atomicAdd(&hist[fbucket(k1, BIAS14)], 1u);
        if (v2) atomicAdd(&hist[fbucket(k2, BIAS14)], 1u);
        if (v3) atomicAdd(&hist[fbucket(k3, BIAS14)], 1u);
        __syncthreads();
        scan1024(hist, cur, wsum, &s_B, t);
        __syncthreads();
        fast = (s_B >= 1);   // B must be strictly above GTHR's partial bucket
    }

    if (fast) {
        const u32 B = (u32)s_B;
        // scatter bucket-grouped from registers, ONLY buckets >= B (~305 keys)
        if (v0) { u32 bk = fbucket(k0, BIAS14);
                  if (bk >= B) { u32 p = atomicAdd(&cur[bk], 1u); cand[p] = k0; } }
        if (v1) { u32 bk = fbucket(k1, BIAS14);
                  if (bk >= B) { u32 p = atomicAdd(&cur[bk], 1u); cand[p] = k1; } }
        if (v2) { u32 bk = fbucket(k2, BIAS14);
                  if (bk >= B) { u32 p = atomicAdd(&cur[bk], 1u); cand[p] = k2; } }
        if (v3) { u32 bk = fbucket(k3, BIAS14);
                  if (bk >= B) { u32 p = atomicAdd(&cur[bk], 1u); cand[p] = k3; } }
        __syncthreads();
        rank_and_write(cand, hist, cur, B, true, BIAS14, t, b, BX, sx, sy, out);
    } else {
        full_fallback(logits, b, t, cand, hist, cur, wsum, &s_B, BX, sx, sy, out);
    }
}

// no-workspace path: pure per-batch two-pass select
__global__ __launch_bounds__(1024) void select_nows_kernel(
    const float* __restrict__ logits,
    const float* __restrict__ boxes,
    const int*   __restrict__ osz,
    float*       __restrict__ out)
{
    __shared__ u64 cand[NCAND];
    __shared__ u32 hist[NBK];
    __shared__ u32 cur[NBK];
    __shared__ u32 wsum[16];
    __shared__ int s_B;
    const int b = blockIdx.x;
    const int t = threadIdx.x;
    const float sx = (float)osz[1];
    const float sy = (float)osz[0];
    const float4* BX = (const float4*)(boxes + (size_t)b * 4000);
    full_fallback(logits, b, t, cand, hist, cur, wsum, &s_B, BX, sx, sy, out);
}

extern "C" void kernel_launch(void* const* d_in, const int* in_sizes, int n_in,
                              void* d_out, int out_size, void* d_ws, size_t ws_size,
                              hipStream_t stream) {
    const float* logits = (const float*)d_in[0];
    const float* boxes  = (const float*)d_in[1];
    const int*   osz    = (const int*)d_in[2];
    float* out = (float*)d_out;

    const size_t need = 65536 + (size_t)NB * NCAND * sizeof(u64);   // ~7.9 MB
    if (ws_size >= need) {
        u32* gcnt = (u32*)d_ws;                          // NB*NSEG u32 = 40 KB
        u64* gbuf = (u64*)((char*)d_ws + 65536);
        collect_kernel<<<dim3(NB * BPB), dim3(256), 0, stream>>>(logits, gcnt, gbuf);
        select_kernel<<<dim3(NB), dim3(1024), 0, stream>>>(logits, boxes, osz,
                                                           gcnt, gbuf, out);
    } else {
        select_nows_kernel<<<dim3(NB), dim3(1024), 0, stream>>>(logits, boxes, osz, out);
    }
}